// Round 17
// baseline (38.260 us; speedup 1.0000x reference)
//
#include <hip/hip_runtime.h>

// HighOrderActivationB, round 15: read/write PHASE SEPARATION.
// Ledger: r7 LDS-gather fix (67->36.4us) only win. Nulls: MLP(r6), occ(r9),
// store-density(r10), bf16-LDS(r11), NT(r12), XCD-swizzle(r13), bytes(r14).
// All on-CU pipes slack -> theory: DRAM read/write turnaround on the
// fine-grained mixed stream (fill=7.1 pure-write, copy=6.3 long-runs 1:1,
// ours=4.5 fine mix). Test: prefetch ALL per-thread X (24 dwords) into
// registers up front -> block = [read burst][pure write burst].

#define B_BATCH 4096
#define N_GROUPS 1024
#define N_TERMS 27
#define OUT_DIM 8
#define GC 16           // groups per block
#define BC 128          // batch rows per block
#define NIT (BC / 16)   // 8 iterations per thread
#define ROW_STRIDE 220  // dwords: 16B-aligned rows, 8 distinct bank starts

typedef float floatx4 __attribute__((ext_vector_type(4)));

__global__ __launch_bounds__(256)
void hoa_kernel(const float* __restrict__ X,
                const float* __restrict__ P,
                float* __restrict__ out) {
    __shared__ float lds[GC * ROW_STRIDE];   // 14080 B

    const int tid = threadIdx.x;
    const int g0 = blockIdx.x * GC;
    const int b0 = blockIdx.y * BC;

    const int g_local = tid & (GC - 1);
    const int b_slot  = tid >> 4;            // 0..15
    const int g = g0 + g_local;

    // ---- READ BURST 1: all X for this thread -> 24 VGPRs, 24 loads in flight
    float ax[NIT][3];
    #pragma unroll
    for (int it = 0; it < NIT; ++it) {
        const float* xp = X + (size_t)(b0 + b_slot + it * 16) * (N_GROUPS * 3) + g * 3;
        ax[it][0] = xp[0];
        ax[it][1] = xp[1];
        ax[it][2] = xp[2];
    }

    // ---- READ BURST 2: stage params for GC groups: 16 rows x 54 float4 ----
    {
        const floatx4* P4 = (const floatx4*)(P + (size_t)g0 * (N_TERMS * OUT_DIM));
        floatx4* L4 = (floatx4*)lds;
        for (int i = tid; i < GC * 54; i += 256) {
            const int r = i / 54;
            const int c = i - r * 54;
            L4[r * (ROW_STRIDE / 4) + c] = P4[i];
        }
    }
    __syncthreads();

    const float* lg = lds + g_local * ROW_STRIDE;

    // ---- WRITE BURST: pure compute/LDS/store, no global reads ----
    #pragma unroll
    for (int it = 0; it < NIT; ++it) {
        const int b = b0 + b_slot + it * 16;

        const float A0 = ax[it][0];
        const float A1 = ax[it][1];
        const float A2 = ax[it][2];

        float m0 = fabsf(A0), m1 = fabsf(A1), m2 = fabsf(A2);
        int t0 = (A0 >= 0.0f) ? 1 : -1;
        int t1 = (A1 >= 0.0f) ? 3 : -3;
        int t2 = (A2 >= 0.0f) ? 9 : -9;

        // stable ascending 3-sort by magnitude (strict > = stable)
        if (m0 > m1) { float tm=m0; m0=m1; m1=tm; int tt=t0; t0=t1; t1=tt; }
        if (m1 > m2) { float tm=m1; m1=m2; m2=tm; int tt=t1; t1=t2; t2=tt; }
        if (m0 > m1) { float tm=m0; m0=m1; m1=tm; int tt=t0; t0=t1; t1=tt; }

        const float c0 = m0;
        const float c1 = m1 - m0;
        const float c2 = m2 - m1;

        const int i2 = 13 + t2;
        const int i1 = i2 + t1;
        const int i0 = i1 + t0;

        // LDS gathers: 6x ds_read_b128 (0 measured conflicts at this layout)
        const floatx4* r0 = (const floatx4*)(lg + i0 * OUT_DIM);
        const floatx4* r1 = (const floatx4*)(lg + i1 * OUT_DIM);
        const floatx4* r2 = (const floatx4*)(lg + i2 * OUT_DIM);
        const floatx4 g0a = r0[0], g0b = r0[1];
        const floatx4 g1a = r1[0], g1b = r1[1];
        const floatx4 g2a = r2[0], g2b = r2[1];

        const floatx4 oa = c0 * g0a + c1 * g1a + c2 * g2a;
        const floatx4 ob = c0 * g0b + c1 * g1b + c2 * g2b;

        // store: lanes 0..15 cover contiguous 512B per b-slot; L2 merges
        floatx4* op = (floatx4*)(out + (size_t)b * (N_GROUPS * OUT_DIM) + g * OUT_DIM);
        op[0] = oa;
        op[1] = ob;
    }
}

extern "C" void kernel_launch(void* const* d_in, const int* in_sizes, int n_in,
                              void* d_out, int out_size, void* d_ws, size_t ws_size,
                              hipStream_t stream) {
    const float* X = (const float*)d_in[0];
    const float* P = (const float*)d_in[1];
    float* out = (float*)d_out;

    dim3 grid(N_GROUPS / GC, B_BATCH / BC);   // (64, 32) = 2048 blocks = 8/CU
    hoa_kernel<<<grid, 256, 0, stream>>>(X, P, out);
}